// Round 18
// baseline (89.791 us; speedup 1.0000x reference)
//
#include <hip/hip_runtime.h>
#include <stdint.h>

using u16 = unsigned short;
using u32 = unsigned int;

typedef __attribute__((ext_vector_type(8))) short short8;
typedef __attribute__((ext_vector_type(4))) float f32x4;
typedef __attribute__((ext_vector_type(16))) float f32x16;

// ---------- helpers ----------
__device__ __forceinline__ u16 f2bf(float f) {
  u32 u = __builtin_bit_cast(u32, f);
  u = (u + 0x7fffu + ((u >> 16) & 1u)) >> 16;  // RNE
  return (u16)u;
}

__device__ __forceinline__ u32 cvtpk(float lo, float hi) {
  u32 r;
  asm("v_cvt_pk_bf16_f32 %0, %1, %2" : "=v"(r) : "v"(lo), "v"(hi));
  return r;
}

__device__ __forceinline__ short8 ld16(const u16* p) {
  uint4 v = *(const uint4*)p;
  union { uint4 u; short8 s; } c; c.u = v; return c.s;
}

__device__ __forceinline__ void gload_lds16(const void* g, void* l) {
  __builtin_amdgcn_global_load_lds(
      (const __attribute__((address_space(1))) void*)g,
      (__attribute__((address_space(3))) void*)l, 16, 0, 0);
}

__device__ __forceinline__ f32x16 mfma32(short8 a, short8 b, f32x16 c) {
  return __builtin_amdgcn_mfma_f32_32x32x16_bf16(a, b, c, 0, 0, 0);
}

// ---------- fused prep: convert hs -> bf16; transpose+convert both weights ----------
__global__ __launch_bounds__(256) void k_prep(const float* __restrict__ hs,
                                              const float* __restrict__ wqkv,
                                              const float* __restrict__ wo,
                                              u16* __restrict__ hsb,
                                              u16* __restrict__ wqkvT,
                                              u16* __restrict__ woT) {
  __shared__ float tile[32][33];
  const int bid = blockIdx.x;
  if (bid < 4096) {
    int i = bid * 256 + threadIdx.x;
    float4 v = ((const float4*)hs)[i];
    ushort4 o;
    o.x = f2bf(v.x); o.y = f2bf(v.y); o.z = f2bf(v.z); o.w = f2bf(v.w);
    ((ushort4*)hsb)[i] = o;
    return;
  }
  const float* in; u16* out; int R, C, bx, by;
  if (bid < 5632) {
    int idx = bid - 4096;                 // wqkv: [1024][1536] -> [1536][1024]
    in = wqkv; out = wqkvT; R = 1024; C = 1536;
    bx = idx % 48; by = idx / 48;
  } else {
    int idx = bid - 5632;                 // wo: [1024][1024] -> [1024][1024]
    in = wo; out = woT; R = 1024; C = 1024;
    bx = idx & 31; by = idx >> 5;
  }
  int c0 = bx * 32, r0 = by * 32;
  int tx = threadIdx.x & 31, ty = threadIdx.x >> 5;
#pragma unroll
  for (int i = 0; i < 4; ++i) {
    int r = ty + 8 * i;
    tile[r][tx] = in[(size_t)(r0 + r) * C + c0 + tx];
  }
  __syncthreads();
#pragma unroll
  for (int i = 0; i < 4; ++i) {
    int r = ty + 8 * i;
    out[(size_t)(c0 + r) * R + r0 + tx] = f2bf(tile[tx][r]);
  }
}

// ---------- GEMM1: qkv = hsb(4096x1024) * Wqkv, 64x128 tile, BK=64 ----------
// Depth-3 counted pipeline (T4): 3 LDS buffers; per iter: vmcnt(6) waits only for the
// OLDEST stage (6 loads/thread/stage; newer stage stays in flight), barrier, issue
// STAGE(kt+2), compute. Each stage gets ~2 compute phases to land vs 1 in the 2-phase.
// LDS 72KB -> 2 blocks/CU (was 3): stall-vs-occupancy tradeoff under test.
__global__ __launch_bounds__(256, 2) void k_gemm_qkv(
    const u16* __restrict__ A, const u16* __restrict__ BT,
    u16* __restrict__ qb, u16* __restrict__ kb, u16* __restrict__ vbT) {
  const int K = 1024;
  __shared__ __align__(16) u16 As[3][64 * 64];
  __shared__ __align__(16) u16 Bs[3][128 * 64];
  const int t = threadIdx.x;
  const int l = t & 63;
  const int wid = t >> 6;
  const int wr = wid >> 1, wc = wid & 1;  // wave tile 32x64
  const int lr = l & 15, lg = l >> 4;
  const int cpx = (int)gridDim.x >> 3;
  const int nb = (blockIdx.x & 7) * cpx + ((int)blockIdx.x >> 3);
  const int mt = nb / 12, nt = nb % 12;
  const int m0 = mt << 6, n0 = nt << 7;

  f32x4 zero = {0.f, 0.f, 0.f, 0.f};
  f32x4 acc[2][4];
#pragma unroll
  for (int i = 0; i < 2; ++i)
#pragma unroll
    for (int j = 0; j < 4; ++j) acc[i][j] = zero;

  const u16* Ab = A + (size_t)m0 * K;
  const u16* Bb = BT + (size_t)n0 * K;

  auto STAGE = [&](int kt, int bsel) {
    const u16* Ak = Ab + kt * 64;
    const u16* Bk = Bb + kt * 64;
#pragma unroll
    for (int i = 0; i < 2; ++i) {
      int o16 = i * 256 + t;
      int row = o16 >> 3, c = o16 & 7;
      int sc = c ^ (row & 7);
      gload_lds16(Ak + (size_t)row * K + sc * 8, &As[bsel][o16 * 8]);
    }
#pragma unroll
    for (int i = 0; i < 4; ++i) {
      int o16 = i * 256 + t;
      int row = o16 >> 3, c = o16 & 7;
      int sc = c ^ (row & 7);
      gload_lds16(Bk + (size_t)row * K + sc * 8, &Bs[bsel][o16 * 8]);
    }
  };

  STAGE(0, 0);
  STAGE(1, 1);

  int cur = 0;                 // kt % 3
  for (int kt = 0; kt < 16; ++kt) {
    // wait for the OLDEST stage only (newer stage's 6 loads stay in flight)
    if (kt + 1 < 16) { asm volatile("s_waitcnt vmcnt(6)" ::: "memory"); }
    else             { asm volatile("s_waitcnt vmcnt(0)" ::: "memory"); }
    __builtin_amdgcn_s_barrier();   // staged buf[cur] visible; all waves done with buf[cur^...]
    if (kt + 2 < 16) {
      int nxt2 = cur - 1 < 0 ? 2 : cur - 1;  // (kt+2)%3 == (kt-1)%3
      STAGE(kt + 2, nxt2);
    }
#pragma unroll
    for (int ks = 0; ks < 2; ++ks) {
      short8 a[2], b[4];
#pragma unroll
      for (int mi = 0; mi < 2; ++mi) {
        int row = wr * 32 + mi * 16 + lr;
        int c = (ks * 4 + lg) ^ (row & 7);
        a[mi] = ld16(&As[cur][(row * 8 + c) * 8]);
      }
#pragma unroll
      for (int ni = 0; ni < 4; ++ni) {
        int row = wc * 64 + ni * 16 + lr;
        int c = (ks * 4 + lg) ^ (row & 7);
        b[ni] = ld16(&Bs[cur][(row * 8 + c) * 8]);
      }
#pragma unroll
      for (int mi = 0; mi < 2; ++mi)
#pragma unroll
        for (int ni = 0; ni < 4; ++ni)
          acc[mi][ni] = __builtin_amdgcn_mfma_f32_16x16x32_bf16(a[mi], b[ni], acc[mi][ni], 0, 0, 0);
    }
    cur = cur + 1 == 3 ? 0 : cur + 1;
  }

#pragma unroll
  for (int mi = 0; mi < 2; ++mi) {
#pragma unroll
    for (int ni = 0; ni < 4; ++ni) {
#pragma unroll
      for (int r = 0; r < 4; ++r) {
        float v = acc[mi][ni][r];
        int m = m0 + wr * 32 + mi * 16 + 4 * lg + r;
        int n = n0 + wc * 64 + ni * 16 + lr;
        int bb = m >> 11, s = m & 2047;
        int tau = s >> 5, i32e = s & 31;
        if (n < 1024) {
          int h = n >> 6, d = n & 63;
          int kc = d >> 4, hi2 = (d >> 3) & 1, e = d & 7;
          // fold SCALE (1/8) * log2(e): softmax runs in exp2 domain
          qb[((size_t)(bb * 16 + h)) * 131072 +
             (size_t)((tau * 4 + kc) * 64 + (hi2 << 5 | i32e)) * 8 + e] = f2bf(v * 0.18033688f);
        } else if (n < 1280) {
          int g = (n - 1024) >> 6, d = n & 63;
          int kc = d >> 4, hi2 = (d >> 3) & 1, e = d & 7;
          kb[((size_t)(bb * 4 + g)) * 131072 +
             (size_t)((tau * 4 + kc) * 64 + (hi2 << 5 | i32e)) * 8 + e] = f2bf(v);
        } else {
          int g = (n - 1280) >> 6, dT = n & 63;
          int c = (s >> 4) & 1, hi2 = (s >> 3) & 1, e = s & 7;
          int dd = dT >> 5, i32v = dT & 31;
          vbT[((size_t)(bb * 4 + g)) * 131072 +
              (size_t)(((tau * 2 + dd) * 2 + c) * 64 + (hi2 << 5 | i32v)) * 8 + e] = f2bf(v);
        }
      }
    }
  }
}

// ---------- GEMM2: out(4096x1024 fp32) = attn(4096x1024 bf16) * Wo, 64x128 tile ----------
// Depth-3 counted pipeline (same structure as GEMM1); LDS 72KB -> 2/CU (unchanged occupancy).
__global__ __launch_bounds__(256, 2) void k_gemm_out(
    const u16* __restrict__ A, const u16* __restrict__ BT, float* __restrict__ out) {
  const int K = 1024, N = 1024;
  __shared__ __align__(16) u16 As[3][64 * 64];
  __shared__ __align__(16) u16 Bs[3][128 * 64];
  const int t = threadIdx.x;
  const int l = t & 63;
  const int wid = t >> 6;
  const int wr = wid >> 1, wc = wid & 1;  // wave tile 32x64
  const int lr = l & 15, lg = l >> 4;
  const int cpx = (int)gridDim.x >> 3;
  const int nb = (blockIdx.x & 7) * cpx + ((int)blockIdx.x >> 3);
  const int mt = nb >> 3, nt = nb & 7;
  const int m0 = mt << 6, n0 = nt << 7;

  f32x4 zero = {0.f, 0.f, 0.f, 0.f};
  f32x4 acc[2][4];
#pragma unroll
  for (int i = 0; i < 2; ++i)
#pragma unroll
    for (int j = 0; j < 4; ++j) acc[i][j] = zero;

  const u16* Ab = A + (size_t)m0 * K;
  const u16* Bb = BT + (size_t)n0 * K;

  auto STAGE = [&](int kt, int bsel) {
    const u16* Ak = Ab + kt * 64;
    const u16* Bk = Bb + kt * 64;
#pragma unroll
    for (int i = 0; i < 2; ++i) {
      int o16 = i * 256 + t;
      int row = o16 >> 3, c = o16 & 7;
      int sc = c ^ (row & 7);
      gload_lds16(Ak + (size_t)row * K + sc * 8, &As[bsel][o16 * 8]);
    }
#pragma unroll
    for (int i = 0; i < 4; ++i) {
      int o16 = i * 256 + t;
      int row = o16 >> 3, c = o16 & 7;
      int sc = c ^ (row & 7);
      gload_lds16(Bk + (size_t)row * K + sc * 8, &Bs[bsel][o16 * 8]);
    }
  };

  STAGE(0, 0);
  STAGE(1, 1);

  int cur = 0;
  for (int kt = 0; kt < 16; ++kt) {
    if (kt + 1 < 16) { asm volatile("s_waitcnt vmcnt(6)" ::: "memory"); }
    else             { asm volatile("s_waitcnt vmcnt(0)" ::: "memory"); }
    __builtin_amdgcn_s_barrier();
    if (kt + 2 < 16) {
      int nxt2 = cur - 1 < 0 ? 2 : cur - 1;
      STAGE(kt + 2, nxt2);
    }
#pragma unroll
    for (int ks = 0; ks < 2; ++ks) {
      short8 a[2], b[4];
#pragma unroll
      for (int mi = 0; mi < 2; ++mi) {
        int row = wr * 32 + mi * 16 + lr;
        int c = (ks * 4 + lg) ^ (row & 7);
        a[mi] = ld16(&As[cur][(row * 8 + c) * 8]);
      }
#pragma unroll
      for (int ni = 0; ni < 4; ++ni) {
        int row = wc * 64 + ni * 16 + lr;
        int c = (ks * 4 + lg) ^ (row & 7);
        b[ni] = ld16(&Bs[cur][(row * 8 + c) * 8]);
      }
#pragma unroll
      for (int mi = 0; mi < 2; ++mi)
#pragma unroll
        for (int ni = 0; ni < 4; ++ni)
          acc[mi][ni] = __builtin_amdgcn_mfma_f32_16x16x32_bf16(a[mi], b[ni], acc[mi][ni], 0, 0, 0);
    }
    cur = cur + 1 == 3 ? 0 : cur + 1;
  }

#pragma unroll
  for (int mi = 0; mi < 2; ++mi)
#pragma unroll
    for (int ni = 0; ni < 4; ++ni)
#pragma unroll
      for (int r = 0; r < 4; ++r) {
        int m = m0 + wr * 32 + mi * 16 + 4 * lg + r;
        int n = n0 + wc * 64 + ni * 16 + lr;
        out[(size_t)m * N + n] = acc[mi][ni][r];
      }
}

// ---------- attention: causal GQA, swapped 32x32 QK^T, fixed-max, QBLK=64 pair-sharing ----------
// (round-14 config, best measured)
__global__ __launch_bounds__(256, 1) void k_attn(const u16* __restrict__ qbuf,
                                                 const u16* __restrict__ kbuf,
                                                 const u16* __restrict__ vbuf,
                                                 u16* __restrict__ attn) {
  __shared__ float osh[2][4096];
  __shared__ float lsh[2][128];
  const int t = threadIdx.x;
  const int l = t & 63, wid = t >> 6;
  const int i32 = l & 31, hi = l >> 5;
  const int bh = blockIdx.x >> 3;
  const int jj = blockIdx.x & 7;
  const int b = bh >> 4, h = bh & 15, g = h >> 2;  // rep=4
  const int slot = wid >> 1, w01 = wid & 1;
  const int cc = jj + slot * 8;       // couple index 0..15
  const int pA = cc, pB = 31 - cc;    // pair indices; nblk(pair p) = p+1
  const int split = 16 - cc;          // wave0's pairB prefix length

  const u16* qp = qbuf + ((size_t)(b * 16 + h)) * 131072;
  const u16* kp = kbuf + ((size_t)(b * 4 + g)) * 131072;
  const u16* vp = vbuf + ((size_t)(b * 4 + g)) * 131072;

  f32x16 z16 = {0.f, 0.f, 0.f, 0.f, 0.f, 0.f, 0.f, 0.f,
                0.f, 0.f, 0.f, 0.f, 0.f, 0.f, 0.f, 0.f};
  short8 qfa[4], qfb[4];
  f32x16 oa[2], ob[2];
  float la, lb;
  short8 kA[2][4], kB[2][4];

  auto LOADQ = [&](int p) {
#pragma unroll
    for (int kc = 0; kc < 4; ++kc) {
      qfa[kc] = ld16(qp + ((size_t)((2 * p) * 4 + kc) * 64 + l) * 8);
      qfb[kc] = ld16(qp + ((size_t)((2 * p + 1) * 4 + kc) * 64 + l) * 8);
    }
  };

  auto LOADK = [&](short8(&kf)[2][4], int kv0) {
#pragma unroll
    for (int mf = 0; mf < 2; ++mf)
#pragma unroll
      for (int kc = 0; kc < 4; ++kc)
        kf[mf][kc] = ld16(kp + ((size_t)((((kv0 >> 5) + mf) * 4 + kc)) * 64 + l) * 8);
  };

  auto SOFTPV = [&](f32x16(&sc)[2], short8(&vf)[2][2][2], f32x16(&o)[2], float& ls,
                    bool dmask, int ilocb) {
    if (dmask) {
#pragma unroll
      for (int mf = 0; mf < 2; ++mf)
#pragma unroll
        for (int R = 0; R < 16; ++R) {
          int j2 = 32 * mf + (R & 3) + 8 * (R >> 2) + 4 * hi;
          if (j2 > ilocb + i32) sc[mf][R] = -1e30f;
        }
    }
    float s0 = 0.f, s1 = 0.f, s2 = 0.f, s3 = 0.f;
#pragma unroll
    for (int mf = 0; mf < 2; ++mf)
#pragma unroll
      for (int R = 0; R < 16; R += 4) {
        float p0 = __builtin_amdgcn_exp2f(sc[mf][R]);
        float p1 = __builtin_amdgcn_exp2f(sc[mf][R + 1]);
        float p2 = __builtin_amdgcn_exp2f(sc[mf][R + 2]);
        float p3 = __builtin_amdgcn_exp2f(sc[mf][R + 3]);
        sc[mf][R] = p0; sc[mf][R + 1] = p1; sc[mf][R + 2] = p2; sc[mf][R + 3] = p3;
        s0 += p0; s1 += p1; s2 += p2; s3 += p3;
      }
    ls += (s0 + s1) + (s2 + s3);
    short8 pb[2][2];
#pragma unroll
    for (int mf = 0; mf < 2; ++mf)
#pragma unroll
      for (int c = 0; c < 2; ++c) {
        union { u32 w[4]; short8 s8; } U;
#pragma unroll
        for (int q = 0; q < 2; ++q) {
          u32 wa = cvtpk(sc[mf][8 * c + 2 * q], sc[mf][8 * c + 2 * q + 1]);
          u32 wb = cvtpk(sc[mf][8 * c + 4 + 2 * q], sc[mf][8 * c + 4 + 2 * q + 1]);
          auto rr = __builtin_amdgcn_permlane32_swap(wa, wb, false, false);
          U.w[q] = (u32)rr[0];
          U.w[2 + q] = (u32)rr[1];
        }
        pb[mf][c] = U.s8;
      }
    __builtin_amdgcn_s_setprio(1);
#pragma unroll
    for (int mf = 0; mf < 2; ++mf)
#pragma unroll
      for (int c = 0; c < 2; ++c) {
        o[0] = mfma32(vf[0][mf][c], pb[mf][c], o[0]);
        o[1] = mfma32(vf[1][mf][c], pb[mf][c], o[1]);
      }
    __builtin_amdgcn_s_setprio(0);
  };

  auto PROCESS = [&](short8(&kf)[2][4], short8(&kn)[2][4], bool pref, int n, int p) {
    const int kv0 = n * 64;
    short8 vf[2][2][2];
#pragma unroll
    for (int mf = 0; mf < 2; ++mf)
#pragma unroll
      for (int dd = 0; dd < 2; ++dd)
#pragma unroll
        for (int c = 0; c < 2; ++c)
          vf[dd][mf][c] = ld16(vp + ((size_t)((((kv0 >> 5) + mf) * 2 + dd) * 2 + c) * 64 + l) * 8);

    const bool dmask = (n == p);

    f32x16 sc[2];
    __builtin_amdgcn_s_setprio(1);
    sc[0] = mfma32(kf[0][0], qfa[0], z16);
    sc[1] = mfma32(kf[1][0], qfa[0], z16);
#pragma unroll
    for (int kc = 1; kc < 4; ++kc) {
      sc[0] = mfma32(kf[0][kc], qfa[kc], sc[0]);
      sc[1] = mfma32(kf[1][kc], qfa[kc], sc[1]);
    }
    __builtin_amdgcn_s_setprio(0);
    if (pref) LOADK(kn, kv0 + 64);
    SOFTPV(sc, vf, oa, la, dmask, 0);

    f32x16 sd[2];
    __builtin_amdgcn_s_setprio(1);
    sd[0] = mfma32(kf[0][0], qfb[0], z16);
    sd[1] = mfma32(kf[1][0], qfb[0], z16);
#pragma unroll
    for (int kc = 1; kc < 4; ++kc) {
      sd[0] = mfma32(kf[0][kc], qfb[kc], sd[0]);
      sd[1] = mfma32(kf[1][kc], qfb[kc], sd[1]);
    }
    __builtin_amdgcn_s_setprio(0);
    SOFTPV(sd, vf, ob, lb, dmask, 32);
  };

  auto RUN = [&](int p, int n0, int n1) {
    if (n0 >= n1) return;
    LOADQ(p);
    LOADK(kA, n0 * 64);
    int n = n0;
    while (true) {
      PROCESS(kA, kB, n + 1 < n1, n, p);
      if (++n >= n1) break;
      PROCESS(kB, kA, n + 1 < n1, n, p);
      if (++n >= n1) break;
    }
  };

  auto STOREPAIR = [&](int p) {
#pragma unroll
    for (int po = 0; po < 2; ++po) {
      float ls = (po == 0) ? la : lb;
      f32x16* o = (po == 0) ? oa : ob;
      float tot;
      {
        u32 su = __builtin_bit_cast(u32, ls);
        auto rr = __builtin_amdgcn_permlane32_swap(su, su, false, false);
        tot = __builtin_bit_cast(float, (u32)rr[0]) + __builtin_bit_cast(float, (u32)rr[1]);
      }
      float inv = 1.f / tot;
      u16* ao = attn + ((size_t)(b * 2048 + (2 * p + po) * 32)) * 1024 + h * 64;
#pragma unroll
      for (int dd = 0; dd < 2; ++dd) {
#pragma unroll
        for (int R = 0; R < 16; R += 2) {
          int d = dd * 32 + (R & 3) + 8 * (R >> 2) + 4 * hi;
          u32 w = cvtpk(o[dd][R] * inv, o[dd][R + 1] * inv);
          *(u32*)(ao + (size_t)i32 * 1024 + d) = w;
        }
      }
    }
  };

  oa[0] = z16; oa[1] = z16; ob[0] = z16; ob[1] = z16; la = 0.f; lb = 0.f;
  if (w01 == 0) {
    RUN(pA, 0, pA + 1);
    STOREPAIR(pA);
    oa[0] = z16; oa[1] = z16; ob[0] = z16; ob[1] = z16; la = 0.f; lb = 0.f;
    RUN(pB, 0, split);
    float* dst = &osh[slot][0];
#pragma unroll
    for (int po = 0; po < 2; ++po) {
      f32x16* o = (po == 0) ? oa : ob;
#pragma unroll
      for (int dd = 0; dd < 2; ++dd) {
        float4* d4 = (float4*)&dst[((po * 2 + dd) * 64 + l) * 16];
#pragma unroll
        for (int q = 0; q < 4; ++q) {
          float4 v4;
          v4.x = o[dd][4 * q]; v4.y = o[dd][4 * q + 1];
          v4.z = o[dd][4 * q + 2]; v4.w = o[dd][4 * q + 3];
          d4[q] = v4;
        }
      }
    }
    lsh[slot][l] = la;
    lsh[slot][64 + l] = lb;
  } else {
    RUN(pB, split, pB + 1);
  }
  __syncthreads();
  if (w01 == 1) {
    const float* src = &osh[slot][0];
#pragma unroll
    for (int po = 0; po < 2; ++po) {
      f32x16* o = (po == 0) ? oa : ob;
#pragma unroll
      for (int dd = 0; dd < 2; ++dd) {
        const float4* s4 = (const float4*)&src[((po * 2 + dd) * 64 + l) * 16];
#pragma unroll
        for (int q = 0; q < 4; ++q) {
          float4 v4 = s4[q];
          o[dd][4 * q] += v4.x; o[dd][4 * q + 1] += v4.y;
          o[dd][4 * q + 2] += v4.z; o[dd][4 * q + 3] += v4.w;
        }
      }
    }
    la += lsh[slot][l];
    lb += lsh[slot][64 + l];
    STOREPAIR(pB);
  }
}

// ---------- launch ----------
extern "C" void kernel_launch(void* const* d_in, const int* in_sizes, int n_in,
                              void* d_out, int out_size, void* d_ws, size_t ws_size,
                              hipStream_t stream) {
  const float* hs = (const float*)d_in[0];    // [2,2048,1024]
  const float* wqkv = (const float*)d_in[1];  // [1024,1536]
  const float* wo = (const float*)d_in[2];    // [1024,1024]
  float* out = (float*)d_out;                 // [2,2048,1024] fp32
  u16* ws = (u16*)d_ws;

  u16* hsb = ws;                   // 4096*1024
  u16* wqkvT = hsb + 4194304;      // 1536*1024
  u16* woT = wqkvT + 1572864;      // 1024*1024
  u16* qb = woT + 1048576;         // packed Q: 32 * 131072
  u16* kb = qb + 4194304;          // packed K: 8 * 131072
  u16* vb = kb + 1048576;          // packed V: 8 * 131072
  u16* attn = vb + 1048576;        // 4096*1024
  (void)in_sizes; (void)n_in; (void)out_size; (void)ws_size;

  k_prep<<<6656, 256, 0, stream>>>(hs, wqkv, wo, hsb, wqkvT, woT);
  k_gemm_qkv<<<768, 256, 0, stream>>>(hsb, wqkvT, qb, kb, vb);
  k_attn<<<256, 256, 0, stream>>>(qb, kb, vb, attn);
  k_gemm_out<<<512, 256, 0, stream>>>(attn, woT, out);
}

// Round 19
// 84.137 us; speedup vs baseline: 1.0672x; 1.0672x over previous
//
#include <hip/hip_runtime.h>
#include <stdint.h>

using u16 = unsigned short;
using u32 = unsigned int;

typedef __attribute__((ext_vector_type(8))) short short8;
typedef __attribute__((ext_vector_type(4))) float f32x4;
typedef __attribute__((ext_vector_type(16))) float f32x16;

// ---------- helpers ----------
__device__ __forceinline__ u16 f2bf(float f) {
  u32 u = __builtin_bit_cast(u32, f);
  u = (u + 0x7fffu + ((u >> 16) & 1u)) >> 16;  // RNE
  return (u16)u;
}

__device__ __forceinline__ u32 cvtpk(float lo, float hi) {
  u32 r;
  asm("v_cvt_pk_bf16_f32 %0, %1, %2" : "=v"(r) : "v"(lo), "v"(hi));
  return r;
}

__device__ __forceinline__ short8 ld16(const u16* p) {
  uint4 v = *(const uint4*)p;
  union { uint4 u; short8 s; } c; c.u = v; return c.s;
}

__device__ __forceinline__ void gload_lds16(const void* g, void* l) {
  __builtin_amdgcn_global_load_lds(
      (const __attribute__((address_space(1))) void*)g,
      (__attribute__((address_space(3))) void*)l, 16, 0, 0);
}

__device__ __forceinline__ f32x16 mfma32(short8 a, short8 b, f32x16 c) {
  return __builtin_amdgcn_mfma_f32_32x32x16_bf16(a, b, c, 0, 0, 0);
}

// ---------- fused prep: convert hs -> bf16; transpose+convert both weights ----------
__global__ __launch_bounds__(256) void k_prep(const float* __restrict__ hs,
                                              const float* __restrict__ wqkv,
                                              const float* __restrict__ wo,
                                              u16* __restrict__ hsb,
                                              u16* __restrict__ wqkvT,
                                              u16* __restrict__ woT) {
  __shared__ float tile[32][33];
  const int bid = blockIdx.x;
  if (bid < 4096) {
    int i = bid * 256 + threadIdx.x;
    float4 v = ((const float4*)hs)[i];
    ushort4 o;
    o.x = f2bf(v.x); o.y = f2bf(v.y); o.z = f2bf(v.z); o.w = f2bf(v.w);
    ((ushort4*)hsb)[i] = o;
    return;
  }
  const float* in; u16* out; int R, C, bx, by;
  if (bid < 5632) {
    int idx = bid - 4096;                 // wqkv: [1024][1536] -> [1536][1024]
    in = wqkv; out = wqkvT; R = 1024; C = 1536;
    bx = idx % 48; by = idx / 48;
  } else {
    int idx = bid - 5632;                 // wo: [1024][1024] -> [1024][1024]
    in = wo; out = woT; R = 1024; C = 1024;
    bx = idx & 31; by = idx >> 5;
  }
  int c0 = bx * 32, r0 = by * 32;
  int tx = threadIdx.x & 31, ty = threadIdx.x >> 5;
#pragma unroll
  for (int i = 0; i < 4; ++i) {
    int r = ty + 8 * i;
    tile[r][tx] = in[(size_t)(r0 + r) * C + c0 + tx];
  }
  __syncthreads();
#pragma unroll
  for (int i = 0; i < 4; ++i) {
    int r = ty + 8 * i;
    out[(size_t)(c0 + r) * R + r0 + tx] = f2bf(tile[tx][r]);
  }
}

// ---------- GEMM1: qkv = hsb(4096x1024) * Wqkv, 64x128 tile, BK=64, 2-phase pipeline ----------
__global__ __launch_bounds__(256, 3) void k_gemm_qkv(
    const u16* __restrict__ A, const u16* __restrict__ BT,
    u16* __restrict__ qb, u16* __restrict__ kb, u16* __restrict__ vbT) {
  const int K = 1024;
  __shared__ __align__(16) u16 As[2][64 * 64];
  __shared__ __align__(16) u16 Bs[2][128 * 64];
  const int t = threadIdx.x;
  const int l = t & 63;
  const int wid = t >> 6;
  const int wr = wid >> 1, wc = wid & 1;  // wave tile 32x64
  const int lr = l & 15, lg = l >> 4;
  const int cpx = (int)gridDim.x >> 3;
  const int nb = (blockIdx.x & 7) * cpx + ((int)blockIdx.x >> 3);
  const int mt = nb / 12, nt = nb % 12;
  const int m0 = mt << 6, n0 = nt << 7;

  f32x4 zero = {0.f, 0.f, 0.f, 0.f};
  f32x4 acc[2][4];
#pragma unroll
  for (int i = 0; i < 2; ++i)
#pragma unroll
    for (int j = 0; j < 4; ++j) acc[i][j] = zero;

  const u16* Ab = A + (size_t)m0 * K;
  const u16* Bb = BT + (size_t)n0 * K;

  auto STAGE = [&](int kt, int bsel) {
    const u16* Ak = Ab + kt * 64;
    const u16* Bk = Bb + kt * 64;
#pragma unroll
    for (int i = 0; i < 2; ++i) {
      int o16 = i * 256 + t;
      int row = o16 >> 3, c = o16 & 7;
      int sc = c ^ (row & 7);
      gload_lds16(Ak + (size_t)row * K + sc * 8, &As[bsel][o16 * 8]);
    }
#pragma unroll
    for (int i = 0; i < 4; ++i) {
      int o16 = i * 256 + t;
      int row = o16 >> 3, c = o16 & 7;
      int sc = c ^ (row & 7);
      gload_lds16(Bk + (size_t)row * K + sc * 8, &Bs[bsel][o16 * 8]);
    }
  };

  STAGE(0, 0);
  asm volatile("s_waitcnt vmcnt(0)" ::: "memory");
  __builtin_amdgcn_s_barrier();

  for (int kt = 0; kt < 16; ++kt) {
    const int cur = kt & 1;
    if (kt + 1 < 16) STAGE(kt + 1, cur ^ 1);
#pragma unroll
    for (int ks = 0; ks < 2; ++ks) {
      short8 a[2], b[4];
#pragma unroll
      for (int mi = 0; mi < 2; ++mi) {
        int row = wr * 32 + mi * 16 + lr;
        int c = (ks * 4 + lg) ^ (row & 7);
        a[mi] = ld16(&As[cur][(row * 8 + c) * 8]);
      }
#pragma unroll
      for (int ni = 0; ni < 4; ++ni) {
        int row = wc * 64 + ni * 16 + lr;
        int c = (ks * 4 + lg) ^ (row & 7);
        b[ni] = ld16(&Bs[cur][(row * 8 + c) * 8]);
      }
#pragma unroll
      for (int mi = 0; mi < 2; ++mi)
#pragma unroll
        for (int ni = 0; ni < 4; ++ni)
          acc[mi][ni] = __builtin_amdgcn_mfma_f32_16x16x32_bf16(a[mi], b[ni], acc[mi][ni], 0, 0, 0);
    }
    asm volatile("s_waitcnt vmcnt(0)" ::: "memory");
    __builtin_amdgcn_s_barrier();
    asm volatile("" ::: "memory");
  }

#pragma unroll
  for (int mi = 0; mi < 2; ++mi) {
#pragma unroll
    for (int ni = 0; ni < 4; ++ni) {
#pragma unroll
      for (int r = 0; r < 4; ++r) {
        float v = acc[mi][ni][r];
        int m = m0 + wr * 32 + mi * 16 + 4 * lg + r;
        int n = n0 + wc * 64 + ni * 16 + lr;
        int bb = m >> 11, s = m & 2047;
        int tau = s >> 5, i32e = s & 31;
        if (n < 1024) {
          int h = n >> 6, d = n & 63;
          int kc = d >> 4, hi2 = (d >> 3) & 1, e = d & 7;
          // fold SCALE (1/8) * log2(e): softmax runs in exp2 domain
          qb[((size_t)(bb * 16 + h)) * 131072 +
             (size_t)((tau * 4 + kc) * 64 + (hi2 << 5 | i32e)) * 8 + e] = f2bf(v * 0.18033688f);
        } else if (n < 1280) {
          int g = (n - 1024) >> 6, d = n & 63;
          int kc = d >> 4, hi2 = (d >> 3) & 1, e = d & 7;
          kb[((size_t)(bb * 4 + g)) * 131072 +
             (size_t)((tau * 4 + kc) * 64 + (hi2 << 5 | i32e)) * 8 + e] = f2bf(v);
        } else {
          int g = (n - 1280) >> 6, dT = n & 63;
          int c = (s >> 4) & 1, hi2 = (s >> 3) & 1, e = s & 7;
          int dd = dT >> 5, i32v = dT & 31;
          vbT[((size_t)(bb * 4 + g)) * 131072 +
              (size_t)(((tau * 2 + dd) * 2 + c) * 64 + (hi2 << 5 | i32v)) * 8 + e] = f2bf(v);
        }
      }
    }
  }
}

// ---------- GEMM2: out(4096x1024 fp32) = attn(4096x1024 bf16) * Wo, 64x128 tile ----------
__global__ __launch_bounds__(256, 2) void k_gemm_out(
    const u16* __restrict__ A, const u16* __restrict__ BT, float* __restrict__ out) {
  const int K = 1024, N = 1024;
  __shared__ __align__(16) u16 As[2][64 * 64];
  __shared__ __align__(16) u16 Bs[2][128 * 64];
  const int t = threadIdx.x;
  const int l = t & 63;
  const int wid = t >> 6;
  const int wr = wid >> 1, wc = wid & 1;  // wave tile 32x64
  const int lr = l & 15, lg = l >> 4;
  const int cpx = (int)gridDim.x >> 3;
  const int nb = (blockIdx.x & 7) * cpx + ((int)blockIdx.x >> 3);
  const int mt = nb >> 3, nt = nb & 7;
  const int m0 = mt << 6, n0 = nt << 7;

  f32x4 zero = {0.f, 0.f, 0.f, 0.f};
  f32x4 acc[2][4];
#pragma unroll
  for (int i = 0; i < 2; ++i)
#pragma unroll
    for (int j = 0; j < 4; ++j) acc[i][j] = zero;

  const u16* Ab = A + (size_t)m0 * K;
  const u16* Bb = BT + (size_t)n0 * K;

  auto STAGE = [&](int kt, int bsel) {
    const u16* Ak = Ab + kt * 64;
    const u16* Bk = Bb + kt * 64;
#pragma unroll
    for (int i = 0; i < 2; ++i) {
      int o16 = i * 256 + t;
      int row = o16 >> 3, c = o16 & 7;
      int sc = c ^ (row & 7);
      gload_lds16(Ak + (size_t)row * K + sc * 8, &As[bsel][o16 * 8]);
    }
#pragma unroll
    for (int i = 0; i < 4; ++i) {
      int o16 = i * 256 + t;
      int row = o16 >> 3, c = o16 & 7;
      int sc = c ^ (row & 7);
      gload_lds16(Bk + (size_t)row * K + sc * 8, &Bs[bsel][o16 * 8]);
    }
  };

  STAGE(0, 0);
  asm volatile("s_waitcnt vmcnt(0)" ::: "memory");
  __builtin_amdgcn_s_barrier();

  for (int kt = 0; kt < 16; ++kt) {
    const int cur = kt & 1;
    if (kt + 1 < 16) STAGE(kt + 1, cur ^ 1);
#pragma unroll
    for (int ks = 0; ks < 2; ++ks) {
      short8 a[2], b[4];
#pragma unroll
      for (int mi = 0; mi < 2; ++mi) {
        int row = wr * 32 + mi * 16 + lr;
        int c = (ks * 4 + lg) ^ (row & 7);
        a[mi] = ld16(&As[cur][(row * 8 + c) * 8]);
      }
#pragma unroll
      for (int ni = 0; ni < 4; ++ni) {
        int row = wc * 64 + ni * 16 + lr;
        int c = (ks * 4 + lg) ^ (row & 7);
        b[ni] = ld16(&Bs[cur][(row * 8 + c) * 8]);
      }
#pragma unroll
      for (int mi = 0; mi < 2; ++mi)
#pragma unroll
        for (int ni = 0; ni < 4; ++ni)
          acc[mi][ni] = __builtin_amdgcn_mfma_f32_16x16x32_bf16(a[mi], b[ni], acc[mi][ni], 0, 0, 0);
    }
    asm volatile("s_waitcnt vmcnt(0)" ::: "memory");
    __builtin_amdgcn_s_barrier();
    asm volatile("" ::: "memory");
  }

#pragma unroll
  for (int mi = 0; mi < 2; ++mi)
#pragma unroll
    for (int ni = 0; ni < 4; ++ni)
#pragma unroll
      for (int r = 0; r < 4; ++r) {
        int m = m0 + wr * 32 + mi * 16 + 4 * lg + r;
        int n = n0 + wc * 64 + ni * 16 + lr;
        out[(size_t)m * N + n] = acc[mi][ni][r];
      }
}

// ---------- attention: causal GQA, swapped 32x32 QK^T, fixed-max, QBLK=64 pair-sharing ----------
// (round-14 config, best measured: each wave owns an adjacent qtile pair sharing all K/V
//  fragment loads; couple (p,31-p) split for wave uniformity; fixed-max combine = LDS sum)
__global__ __launch_bounds__(256, 1) void k_attn(const u16* __restrict__ qbuf,
                                                 const u16* __restrict__ kbuf,
                                                 const u16* __restrict__ vbuf,
                                                 u16* __restrict__ attn) {
  __shared__ float osh[2][4096];
  __shared__ float lsh[2][128];
  const int t = threadIdx.x;
  const int l = t & 63, wid = t >> 6;
  const int i32 = l & 31, hi = l >> 5;
  const int bh = blockIdx.x >> 3;
  const int jj = blockIdx.x & 7;
  const int b = bh >> 4, h = bh & 15, g = h >> 2;  // rep=4
  const int slot = wid >> 1, w01 = wid & 1;
  const int cc = jj + slot * 8;       // couple index 0..15
  const int pA = cc, pB = 31 - cc;    // pair indices; nblk(pair p) = p+1
  const int split = 16 - cc;          // wave0's pairB prefix length

  const u16* qp = qbuf + ((size_t)(b * 16 + h)) * 131072;
  const u16* kp = kbuf + ((size_t)(b * 4 + g)) * 131072;
  const u16* vp = vbuf + ((size_t)(b * 4 + g)) * 131072;

  f32x16 z16 = {0.f, 0.f, 0.f, 0.f, 0.f, 0.f, 0.f, 0.f,
                0.f, 0.f, 0.f, 0.f, 0.f, 0.f, 0.f, 0.f};
  short8 qfa[4], qfb[4];
  f32x16 oa[2], ob[2];
  float la, lb;
  short8 kA[2][4], kB[2][4];

  auto LOADQ = [&](int p) {
#pragma unroll
    for (int kc = 0; kc < 4; ++kc) {
      qfa[kc] = ld16(qp + ((size_t)((2 * p) * 4 + kc) * 64 + l) * 8);
      qfb[kc] = ld16(qp + ((size_t)((2 * p + 1) * 4 + kc) * 64 + l) * 8);
    }
  };

  auto LOADK = [&](short8(&kf)[2][4], int kv0) {
#pragma unroll
    for (int mf = 0; mf < 2; ++mf)
#pragma unroll
      for (int kc = 0; kc < 4; ++kc)
        kf[mf][kc] = ld16(kp + ((size_t)((((kv0 >> 5) + mf) * 4 + kc)) * 64 + l) * 8);
  };

  auto SOFTPV = [&](f32x16(&sc)[2], short8(&vf)[2][2][2], f32x16(&o)[2], float& ls,
                    bool dmask, int ilocb) {
    if (dmask) {
#pragma unroll
      for (int mf = 0; mf < 2; ++mf)
#pragma unroll
        for (int R = 0; R < 16; ++R) {
          int j2 = 32 * mf + (R & 3) + 8 * (R >> 2) + 4 * hi;
          if (j2 > ilocb + i32) sc[mf][R] = -1e30f;
        }
    }
    float s0 = 0.f, s1 = 0.f, s2 = 0.f, s3 = 0.f;
#pragma unroll
    for (int mf = 0; mf < 2; ++mf)
#pragma unroll
      for (int R = 0; R < 16; R += 4) {
        float p0 = __builtin_amdgcn_exp2f(sc[mf][R]);
        float p1 = __builtin_amdgcn_exp2f(sc[mf][R + 1]);
        float p2 = __builtin_amdgcn_exp2f(sc[mf][R + 2]);
        float p3 = __builtin_amdgcn_exp2f(sc[mf][R + 3]);
        sc[mf][R] = p0; sc[mf][R + 1] = p1; sc[mf][R + 2] = p2; sc[mf][R + 3] = p3;
        s0 += p0; s1 += p1; s2 += p2; s3 += p3;
      }
    ls += (s0 + s1) + (s2 + s3);
    short8 pb[2][2];
#pragma unroll
    for (int mf = 0; mf < 2; ++mf)
#pragma unroll
      for (int c = 0; c < 2; ++c) {
        union { u32 w[4]; short8 s8; } U;
#pragma unroll
        for (int q = 0; q < 2; ++q) {
          u32 wa = cvtpk(sc[mf][8 * c + 2 * q], sc[mf][8 * c + 2 * q + 1]);
          u32 wb = cvtpk(sc[mf][8 * c + 4 + 2 * q], sc[mf][8 * c + 4 + 2 * q + 1]);
          auto rr = __builtin_amdgcn_permlane32_swap(wa, wb, false, false);
          U.w[q] = (u32)rr[0];
          U.w[2 + q] = (u32)rr[1];
        }
        pb[mf][c] = U.s8;
      }
    __builtin_amdgcn_s_setprio(1);
#pragma unroll
    for (int mf = 0; mf < 2; ++mf)
#pragma unroll
      for (int c = 0; c < 2; ++c) {
        o[0] = mfma32(vf[0][mf][c], pb[mf][c], o[0]);
        o[1] = mfma32(vf[1][mf][c], pb[mf][c], o[1]);
      }
    __builtin_amdgcn_s_setprio(0);
  };

  auto PROCESS = [&](short8(&kf)[2][4], short8(&kn)[2][4], bool pref, int n, int p) {
    const int kv0 = n * 64;
    short8 vf[2][2][2];
#pragma unroll
    for (int mf = 0; mf < 2; ++mf)
#pragma unroll
      for (int dd = 0; dd < 2; ++dd)
#pragma unroll
        for (int c = 0; c < 2; ++c)
          vf[dd][mf][c] = ld16(vp + ((size_t)((((kv0 >> 5) + mf) * 2 + dd) * 2 + c) * 64 + l) * 8);

    const bool dmask = (n == p);

    f32x16 sc[2];
    __builtin_amdgcn_s_setprio(1);
    sc[0] = mfma32(kf[0][0], qfa[0], z16);
    sc[1] = mfma32(kf[1][0], qfa[0], z16);
#pragma unroll
    for (int kc = 1; kc < 4; ++kc) {
      sc[0] = mfma32(kf[0][kc], qfa[kc], sc[0]);
      sc[1] = mfma32(kf[1][kc], qfa[kc], sc[1]);
    }
    __builtin_amdgcn_s_setprio(0);
    if (pref) LOADK(kn, kv0 + 64);
    SOFTPV(sc, vf, oa, la, dmask, 0);

    f32x16 sd[2];
    __builtin_amdgcn_s_setprio(1);
    sd[0] = mfma32(kf[0][0], qfb[0], z16);
    sd[1] = mfma32(kf[1][0], qfb[0], z16);
#pragma unroll
    for (int kc = 1; kc < 4; ++kc) {
      sd[0] = mfma32(kf[0][kc], qfb[kc], sd[0]);
      sd[1] = mfma32(kf[1][kc], qfb[kc], sd[1]);
    }
    __builtin_amdgcn_s_setprio(0);
    SOFTPV(sd, vf, ob, lb, dmask, 32);
  };

  auto RUN = [&](int p, int n0, int n1) {
    if (n0 >= n1) return;
    LOADQ(p);
    LOADK(kA, n0 * 64);
    int n = n0;
    while (true) {
      PROCESS(kA, kB, n + 1 < n1, n, p);
      if (++n >= n1) break;
      PROCESS(kB, kA, n + 1 < n1, n, p);
      if (++n >= n1) break;
    }
  };

  auto STOREPAIR = [&](int p) {
#pragma unroll
    for (int po = 0; po < 2; ++po) {
      float ls = (po == 0) ? la : lb;
      f32x16* o = (po == 0) ? oa : ob;
      float tot;
      {
        u32 su = __builtin_bit_cast(u32, ls);
        auto rr = __builtin_amdgcn_permlane32_swap(su, su, false, false);
        tot = __builtin_bit_cast(float, (u32)rr[0]) + __builtin_bit_cast(float, (u32)rr[1]);
      }
      float inv = 1.f / tot;
      u16* ao = attn + ((size_t)(b * 2048 + (2 * p + po) * 32)) * 1024 + h * 64;
#pragma unroll
      for (int dd = 0; dd < 2; ++dd) {
#pragma unroll
        for (int R = 0; R < 16; R += 2) {
          int d = dd * 32 + (R & 3) + 8 * (R >> 2) + 4 * hi;
          u32 w = cvtpk(o[dd][R] * inv, o[dd][R + 1] * inv);
          *(u32*)(ao + (size_t)i32 * 1024 + d) = w;
        }
      }
    }
  };

  oa[0] = z16; oa[1] = z16; ob[0] = z16; ob[1] = z16; la = 0.f; lb = 0.f;
  if (w01 == 0) {
    RUN(pA, 0, pA + 1);
    STOREPAIR(pA);
    oa[0] = z16; oa[1] = z16; ob[0] = z16; ob[1] = z16; la = 0.f; lb = 0.f;
    RUN(pB, 0, split);
    float* dst = &osh[slot][0];
#pragma unroll
    for (int po = 0; po < 2; ++po) {
      f32x16* o = (po == 0) ? oa : ob;
#pragma unroll
      for (int dd = 0; dd < 2; ++dd) {
        float4* d4 = (float4*)&dst[((po * 2 + dd) * 64 + l) * 16];
#pragma unroll
        for (int q = 0; q < 4; ++q) {
          float4 v4;
          v4.x = o[dd][4 * q]; v4.y = o[dd][4 * q + 1];
          v4.z = o[dd][4 * q + 2]; v4.w = o[dd][4 * q + 3];
          d4[q] = v4;
        }
      }
    }
    lsh[slot][l] = la;
    lsh[slot][64 + l] = lb;
  } else {
    RUN(pB, split, pB + 1);
  }
  __syncthreads();
  if (w01 == 1) {
    const float* src = &osh[slot][0];
#pragma unroll
    for (int po = 0; po < 2; ++po) {
      f32x16* o = (po == 0) ? oa : ob;
#pragma unroll
      for (int dd = 0; dd < 2; ++dd) {
        const float4* s4 = (const float4*)&src[((po * 2 + dd) * 64 + l) * 16];
#pragma unroll
        for (int q = 0; q < 4; ++q) {
          float4 v4 = s4[q];
          o[dd][4 * q] += v4.x; o[dd][4 * q + 1] += v4.y;
          o[dd][4 * q + 2] += v4.z; o[dd][4 * q + 3] += v4.w;
        }
      }
    }
    la += lsh[slot][l];
    lb += lsh[slot][64 + l];
    STOREPAIR(pB);
  }
}

// ---------- launch ----------
extern "C" void kernel_launch(void* const* d_in, const int* in_sizes, int n_in,
                              void* d_out, int out_size, void* d_ws, size_t ws_size,
                              hipStream_t stream) {
  const float* hs = (const float*)d_in[0];    // [2,2048,1024]
  const float* wqkv = (const float*)d_in[1];  // [1024,1536]
  const float* wo = (const float*)d_in[2];    // [1024,1024]
  float* out = (float*)d_out;                 // [2,2048,1024] fp32
  u16* ws = (u16*)d_ws;

  u16* hsb = ws;                   // 4096*1024
  u16* wqkvT = hsb + 4194304;      // 1536*1024
  u16* woT = wqkvT + 1572864;      // 1024*1024
  u16* qb = woT + 1048576;         // packed Q: 32 * 131072
  u16* kb = qb + 4194304;          // packed K: 8 * 131072
  u16* vb = kb + 1048576;          // packed V: 8 * 131072
  u16* attn = vb + 1048576;        // 4096*1024
  (void)in_sizes; (void)n_in; (void)out_size; (void)ws_size;

  k_prep<<<6656, 256, 0, stream>>>(hs, wqkv, wo, hsb, wqkvT, woT);
  k_gemm_qkv<<<768, 256, 0, stream>>>(hsb, wqkvT, qb, kb, vb);
  k_attn<<<256, 256, 0, stream>>>(qb, kb, vb, attn);
  k_gemm_out<<<512, 256, 0, stream>>>(attn, woT, out);
}